// Round 13
// baseline (511.296 us; speedup 1.0000x reference)
//
#include <hip/hip_runtime.h>

typedef __bf16 bf16x8 __attribute__((ext_vector_type(8)));
typedef __bf16 bf16x2_t __attribute__((ext_vector_type(2)));
typedef float f32x4 __attribute__((ext_vector_type(4)));
typedef float f32x16 __attribute__((ext_vector_type(16)));
typedef unsigned int u32x4 __attribute__((ext_vector_type(4)));
typedef unsigned short u16x8 __attribute__((ext_vector_type(8)));

#define EMB 2048
#define NH 16
#define HD 128
#define TSEQ 4096

// ---------- helpers ----------
__device__ __forceinline__ unsigned short f2bf(float x) {
  unsigned int u = __builtin_bit_cast(unsigned int, x);
  u += 0x7fffu + ((u >> 16) & 1u);   // RNE
  return (unsigned short)(u >> 16);
}

__device__ __forceinline__ float bf2f(unsigned short u) {
  unsigned int x = ((unsigned int)u) << 16;
  return __builtin_bit_cast(float, x);
}

__device__ __forceinline__ float ex2(float x) { return __builtin_amdgcn_exp2f(x); }

__device__ __forceinline__ void gl_lds16(const void* g, void* l) {
  __builtin_amdgcn_global_load_lds((__attribute__((address_space(1))) void*)(void*)g,
                                   (__attribute__((address_space(3))) void*)l, 16, 0, 0);
}

template <typename OutT>
__device__ __forceinline__ void store_out(OutT* p, float v) {
  if constexpr (sizeof(OutT) == 2) { *p = f2bf(v); } else { *p = v; }
}

// ---------- fused fp32 -> bf16 convert for all 7 tensors ----------
__global__ __launch_bounds__(256) void cvt_all(const float* __restrict__ q, const float* __restrict__ k,
                                               const float* __restrict__ v, const float* __restrict__ Wq,
                                               const float* __restrict__ Wk, const float* __restrict__ Wv,
                                               const float* __restrict__ Wo,
                                               unsigned short* qb, unsigned short* kb, unsigned short* vb,
                                               unsigned short* Wqb, unsigned short* Wkb, unsigned short* Wvb,
                                               unsigned short* Wob) {
  const int SX = TSEQ * EMB / 8;   // 2^20
  const int SW = EMB * EMB / 8;    // 2^19
  int i = blockIdx.x * 256 + threadIdx.x;
  const float* src; unsigned short* dst; int off;
  if (i < 3 * SX) {
    int seg = i >> 20; off = i & (SX - 1);
    src = (seg == 0) ? q : (seg == 1) ? k : v;
    dst = (seg == 0) ? qb : (seg == 1) ? kb : vb;
  } else {
    int j = i - 3 * SX;
    int seg = j >> 19; off = j & (SW - 1);
    src = (seg == 0) ? Wq : (seg == 1) ? Wk : (seg == 2) ? Wv : Wo;
    dst = (seg == 0) ? Wqb : (seg == 1) ? Wkb : (seg == 2) ? Wvb : Wob;
  }
  const float4* p = (const float4*)src + (size_t)off * 2;
  float4 a = p[0], b = p[1];
  u32x4 r;
  r.x = (unsigned)f2bf(a.x) | ((unsigned)f2bf(a.y) << 16);
  r.y = (unsigned)f2bf(a.z) | ((unsigned)f2bf(a.w) << 16);
  r.z = (unsigned)f2bf(b.x) | ((unsigned)f2bf(b.y) << 16);
  r.w = (unsigned)f2bf(b.z) | ((unsigned)f2bf(b.w) << 16);
  ((u32x4*)dst)[off] = r;
}

// ---------- NT GEMM body: C[M,N] = A[M,K] * B[N,K]^T  (128x128 tile, BK=32) ----------
// r8's proven staging/sync structure (counted-vmcnt double-buffer, both-side swizzle).
template <typename OutT>
__device__ __forceinline__ void gemm_body(const unsigned short* __restrict__ A,
                                          const unsigned short* __restrict__ B,
                                          OutT* __restrict__ C,
                                          int m0, int n0, int N, int K, char* smem, float oscale) {
  const int t = threadIdx.x;
  const int l = t & 63, lg = l >> 4, l15 = l & 15;
  const int w = t >> 6, wm = w >> 1, wn = w & 1;

  f32x4 acc[4][4] = {};

  const int rowS = t >> 2;
  const int cbS = (t & 3) * 16;
  const int swS = cbS ^ ((rowS & 3) << 4);        // pre-swizzled source column byte
  const char* Ab = (const char*)A + ((size_t)(m0 + rowS) * K) * 2;
  const char* Bb = (const char*)B + ((size_t)(n0 + rowS) * K) * 2;
  const size_t rowStep = (size_t)64 * K * 2;

  auto stage = [&](int buf, int kt) {
    const int ktB = kt * 2;
    char* sA = smem + buf * 8192;
    char* sB = smem + 16384 + buf * 8192;
    gl_lds16(Ab + ktB + swS, sA + t * 16);
    gl_lds16(Ab + rowStep + ktB + swS, sA + 4096 + t * 16);   // (row+64)&3 == row&3
    gl_lds16(Bb + ktB + swS, sB + t * 16);
    gl_lds16(Bb + rowStep + ktB + swS, sB + 4096 + t * 16);
  };

  const int nIter = K / 32;
  stage(0, 0);
  int cur = 0;
  for (int it = 0; it < nIter; ++it) {
    if (it + 1 < nIter) {
      stage(cur ^ 1, (it + 1) * 32);
      asm volatile("s_waitcnt vmcnt(4)" ::: "memory");   // wait only for CURRENT tile's stage
    } else {
      asm volatile("s_waitcnt vmcnt(0)" ::: "memory");
    }
    __builtin_amdgcn_s_barrier();

    const char* sA = smem + cur * 8192;
    const char* sB = smem + 16384 + cur * 8192;
    const int rsw = (l15 & 3) << 4;                      // read-side XOR (rows mod 4 = l15&3)
    bf16x8 af[4], bfr[4];
#pragma unroll
    for (int m = 0; m < 4; m++) {
      const int r = wm * 64 + m * 16 + l15;
      af[m] = *(const bf16x8*)(sA + r * 64 + ((lg * 16) ^ rsw));
    }
#pragma unroll
    for (int n = 0; n < 4; n++) {
      const int r = wn * 64 + n * 16 + l15;
      bfr[n] = *(const bf16x8*)(sB + r * 64 + ((lg * 16) ^ rsw));
    }
#pragma unroll
    for (int m = 0; m < 4; m++)
#pragma unroll
      for (int n = 0; n < 4; n++)
        acc[m][n] = __builtin_amdgcn_mfma_f32_16x16x32_bf16(af[m], bfr[n], acc[m][n], 0, 0, 0);

    __builtin_amdgcn_s_barrier();   // all waves done reading buf[cur] before it is restaged
    cur ^= 1;
  }

#pragma unroll
  for (int m = 0; m < 4; m++) {
    int row = m0 + wm * 64 + m * 16 + 4 * lg;
#pragma unroll
    for (int n = 0; n < 4; n++) {
      int col = n0 + wn * 64 + n * 16 + l15;
#pragma unroll
      for (int i = 0; i < 4; i++)
        store_out(C + (size_t)(row + i) * N + col, acc[m][n][i] * oscale);
    }
  }
}

// Fused Q/K/V projections: 1536 blocks, linear grid (r8's proven mapping).
// Q output pre-scaled by 1/sqrt(HD)*log2(e) so attention softmax runs in exp2 domain.
__global__ __launch_bounds__(256) void gemm_qkv(const unsigned short* __restrict__ qb,
                                                const unsigned short* __restrict__ kb,
                                                const unsigned short* __restrict__ vb,
                                                const unsigned short* __restrict__ Wq,
                                                const unsigned short* __restrict__ Wk,
                                                const unsigned short* __restrict__ Wv,
                                                unsigned short* Qo, unsigned short* Ko, unsigned short* Vto) {
  __shared__ char smem[32768];
  const int bx = blockIdx.x;
  const int z = bx >> 9, r = bx & 511;
  const unsigned short* A; const unsigned short* B; unsigned short* C;
  int N, m0, n0; float sc;
  if (z == 0)      { A = qb; B = Wq; C = Qo;  N = EMB;  n0 = (r & 15) << 7; m0 = (r >> 4) << 7; sc = 0.12751743f; }
  else if (z == 1) { A = kb; B = Wk; C = Ko;  N = EMB;  n0 = (r & 15) << 7; m0 = (r >> 4) << 7; sc = 1.0f; }
  else             { A = Wv; B = vb; C = Vto; N = TSEQ; n0 = (r & 31) << 7; m0 = (r >> 5) << 7; sc = 1.0f; }
  gemm_body<unsigned short>(A, B, C, m0, n0, N, EMB, smem, sc);
}

// Output projection -> bf16 y2 (halves y2 traffic; LN reads bf16).
__global__ __launch_bounds__(256) void gemm_o(const unsigned short* __restrict__ A,
                                              const unsigned short* __restrict__ B,
                                              unsigned short* __restrict__ C) {
  __shared__ char smem[32768];
  gemm_body<unsigned short>(A, B, C, blockIdx.y * 128, blockIdx.x * 128, EMB, EMB, smem, 1.0f);
}

// ---------- flash attention (causal), swapped-QK^T, 32x32x16 MFMA, static-max softmax ----------
// KVBLK=32, 1024 UNIFORM blocks of 33 kv-iterations (4 chunks per head-pair), 40 KB LDS
// -> 4 blocks/CU (16 waves/CU). Pair (p,31-p) concatenated kv sequence (Alen=4p+4 A-blocks
// then 128-4p B-blocks = 132 = 4*33). Static max M=8 keeps partials sum-mergeable.
// Slots per pair: A-parts slot = pairBase+chunk, B-parts slot = pairBase+chunk+1 (<=5 total).
__global__ __launch_bounds__(256, 4) void attn_kernel(const unsigned short* __restrict__ Q,
                                                      const unsigned short* __restrict__ Kp,
                                                      const unsigned short* __restrict__ Vt,
                                                      unsigned short* __restrict__ slotsLo,
                                                      unsigned short* __restrict__ slotsHi,
                                                      float* __restrict__ lbuf) {
  __shared__ char sK[2][8192];   // [32 kv][128 hd] bf16 = [32][256B], xor-swz (&15)
  __shared__ char sV[3][8192];   // [128 hd][32 kv] bf16 = [128][64B], xor-swz (&3)
  const int t = threadIdx.x, l = t & 63, w = t >> 6;
  const int l31 = l & 31, hh = l >> 5;
  const int b = blockIdx.x;
  const int h = b >> 6;
  const int p = (b >> 2) & 15;
  const int chunk = b & 3;
  const int pairBase = (h * 16 + p) * 5;
  const int Alen = 4 * p + 4;                 // tile-A kv blocks (32-wide)
  const int startG = chunk * 33;
  const int q0A = 128 * p, q0B = 128 * (31 - p);
  const bool startA = (startG < Alen);
  const int swi = startA ? (Alen - startG) : 999;
  const bool hasSwitch = startA && (swi < 33);   // swi in [1,32]

  int q0 = startA ? q0A : q0B;
  int qrow = q0 + w * 32 + l31;

  auto kvof = [&](int gi) -> int {
    const int g = startG + gi;
    return (g < Alen) ? g * 32 : (g - Alen) * 32;
  };

  auto slotPtr = [&](int s) -> unsigned short* {
    return (s < 768) ? (slotsLo + (size_t)s * 16384) : (slotsHi + (size_t)(s - 768) * 16384);
  };

  bf16x8 qf[8];
#pragma unroll
  for (int kd = 0; kd < 8; kd++)
    qf[kd] = *(const bf16x8*)(Q + (size_t)qrow * EMB + h * HD + kd * 16 + hh * 8);

  f32x16 o[4] = {};
  float l_run = 0.0f;

  const int rK = t >> 4, cK = (t & 15) * 16;   // K staging: 16 rows/pass (256B rows)
  const int rV = t >> 2, cV = (t & 3) * 16;    // V staging: 64 rows/pass (64B rows)
  const char* Kb = (const char*)Kp;
  const char* Vb = (const char*)Vt;

  auto stage = [&](int kbuf, int vbuf, int kv0) {
#pragma unroll
    for (int c = 0; c < 2; c++) {
      int rowK = c * 16 + rK;
      gl_lds16(Kb + (size_t)(kv0 + rowK) * (EMB * 2) + h * (HD * 2) + (cK ^ ((rowK & 15) << 4)),
               sK[kbuf] + c * 4096 + t * 16);
      int rowV = c * 64 + rV;
      gl_lds16(Vb + (size_t)(h * HD + rowV) * (TSEQ * 2) + kv0 * 2 + (cV ^ ((rowV & 3) << 4)),
               sV[vbuf] + c * 4096 + t * 16);
    }
  };

  auto writeout = [&](int slotId) {
    unsigned short* S = slotPtr(slotId);
    const int r = w * 32 + l31;
    float lt = l_run + __shfl_xor(l_run, 32, 64);
    if (hh == 0) lbuf[slotId * 128 + r] = lt;
#pragma unroll
    for (int hdm = 0; hdm < 4; hdm++)
#pragma unroll
      for (int rq = 0; rq < 4; rq++) {
        ushort4 st;
        st.x = f2bf(o[hdm][4 * rq + 0]);
        st.y = f2bf(o[hdm][4 * rq + 1]);
        st.z = f2bf(o[hdm][4 * rq + 2]);
        st.w = f2bf(o[hdm][4 * rq + 3]);
        *(ushort4*)(S + r * 128 + hdm * 32 + 8 * rq + 4 * hh) = st;
      }
  };

  stage(0, 0, kvof(0));
  int kc = 0, vc = 0, vn = 1;
  for (int gi = 0; gi < 33; ++gi) {
    if (hasSwitch && gi == swi) {
      writeout(pairBase + chunk);     // flush tile-A partial
#pragma unroll
      for (int hdm = 0; hdm < 4; hdm++)
#pragma unroll
        for (int i = 0; i < 16; i++) o[hdm][i] = 0.0f;
      l_run = 0.0f;
      q0 = q0B;
      qrow = q0 + w * 32 + l31;
#pragma unroll
      for (int kd = 0; kd < 8; kd++)
        qf[kd] = *(const bf16x8*)(Q + (size_t)qrow * EMB + h * HD + kd * 16 + hh * 8);
    }
    const int kv0 = kvof(gi);
    if (gi + 1 < 33) {
      stage(kc ^ 1, vn, kvof(gi + 1));
      asm volatile("s_waitcnt vmcnt(4)" ::: "memory");   // wait only for THIS tile's stage
    } else {
      asm volatile("s_waitcnt vmcnt(0)" ::: "memory");
    }
    __builtin_amdgcn_s_barrier();

    const char* KB = sK[kc];
    const char* VB = sV[vc];

    // S^T[kv,q]: A = K rows (32 kv), B = Q cols; acc init -8 = static-max shift
    f32x16 s;
#pragma unroll
    for (int i = 0; i < 16; i++) s[i] = -8.0f;
    __builtin_amdgcn_s_setprio(1);
    {
      const int rowA = l31;
      const int swz = (rowA & 15) << 4;
#pragma unroll
      for (int kd = 0; kd < 8; kd++) {
        bf16x8 kf = *(const bf16x8*)(KB + rowA * 256 + ((kd * 32 + hh * 16) ^ swz));
        s = __builtin_amdgcn_mfma_f32_32x32x16_bf16(kf, qf[kd], s, 0, 0, 0);
      }
    }
    __builtin_amdgcn_s_setprio(0);
    __builtin_amdgcn_s_barrier();   // K[kc] reads done -> next iter may restage it

    // ---- static-max softmax (exp2 domain): p = exp2(s - 8) ----
    const bool diag = (kv0 + 32 > q0);
    if (diag) {
#pragma unroll
      for (int i = 0; i < 16; i++)
        if (kv0 + (i & 3) + 8 * (i >> 2) + 4 * hh > qrow) s[i] = -1e30f;
    }
    float psum = 0.0f;
    unsigned int wb[8];   // word m covers kv = 2*(m&1)+8*(m>>1)+4*hh
#pragma unroll
    for (int m = 0; m < 8; m++) {
      float p0 = ex2(s[2 * m + 0]);
      float p1 = ex2(s[2 * m + 1]);
      psum += p0 + p1;
      bf16x2_t pk; pk[0] = (__bf16)p0; pk[1] = (__bf16)p1;
      wb[m] = __builtin_bit_cast(unsigned int, pk);
    }
    l_run += psum;

    // ---- PV: O^T += V^T * P^T (barrier-free) ----
    __builtin_amdgcn_s_setprio(1);
#pragma unroll
    for (int sx = 0; sx < 2; sx++) {
      const int base = 4 * sx;
      const unsigned int a0 = wb[base + 0], a1 = wb[base + 1];
      const unsigned int b0 = wb[base + 2], b1 = wb[base + 3];
      const unsigned int snd0 = hh ? a0 : b0;
      const unsigned int snd1 = hh ? a1 : b1;
      const unsigned int rcv0 = (unsigned int)__shfl_xor((int)snd0, 32, 64);
      const unsigned int rcv1 = (unsigned int)__shfl_xor((int)snd1, 32, 64);
      u32x4 pw;
      pw.x = hh ? rcv0 : a0;
      pw.y = hh ? rcv1 : a1;
      pw.z = hh ? b0 : rcv0;
      pw.w = hh ? b1 : rcv1;
      const bf16x8 pfrag = __builtin_bit_cast(bf16x8, pw);
#pragma unroll
      for (int hdm = 0; hdm < 4; hdm++) {
        const int rowA = hdm * 32 + l31;
        bf16x8 vf = *(const bf16x8*)(VB + rowA * 64 + ((sx * 32 + hh * 16) ^ ((rowA & 3) << 4)));
        o[hdm] = __builtin_amdgcn_mfma_f32_32x32x16_bf16(vf, pfrag, o[hdm], 0, 0, 0);
      }
    }
    __builtin_amdgcn_s_setprio(0);

    kc ^= 1;
    vc = vn;
    vn = (vn == 2) ? 0 : vn + 1;
  }

  const bool endA = startA && !hasSwitch;   // entire chunk inside tile A
  writeout(endA ? (pairBase + chunk) : (pairBase + chunk + 1));
}

// ---------- merge partials -> normalized bf16 y ----------
// 512 blocks = (head, out-tile). Tile A (tt<=15): slots pairBase+0..cA;
// tile B (tt>=16): slots pairBase+cA+1..4, where cA = (p>=8)?1:0.
__global__ __launch_bounds__(256) void merge_kernel(const unsigned short* __restrict__ slotsLo,
                                                    const unsigned short* __restrict__ slotsHi,
                                                    const float* __restrict__ lbuf,
                                                    unsigned short* __restrict__ Y) {
  const int tile = blockIdx.x;
  const int h = tile >> 5, tt = tile & 31;
  const int p = (tt <= 15) ? tt : 31 - tt;
  const int pairBase = (h * 16 + p) * 5;
  const int cA = (p >= 8) ? 1 : 0;
  int s0, ns;
  if (tt <= 15) { s0 = pairBase;          ns = cA + 1; }
  else          { s0 = pairBase + cA + 1; ns = 4 - cA; }
  const int t = threadIdx.x;
  const int r = t >> 1;
  const int c0 = (t & 1) * 64;

  float lsum = 0.0f;
  for (int q = 0; q < ns; q++) lsum += lbuf[(s0 + q) * 128 + r];
  const float inv = 1.0f / lsum;

  const unsigned short* Sp[4];
  for (int q = 0; q < ns; q++) {
    const int s = s0 + q;
    Sp[q] = ((s < 768) ? (slotsLo + (size_t)s * 16384) : (slotsHi + (size_t)(s - 768) * 16384))
            + r * 128 + c0;
  }

  unsigned short* yp = Y + (size_t)(128 * tt + r) * EMB + h * HD + c0;
#pragma unroll
  for (int j = 0; j < 8; j++) {
    float acc8[8] = {};
    for (int q = 0; q < ns; q++) {
      u16x8 a = ((const u16x8*)Sp[q])[j];
#pragma unroll
      for (int e = 0; e < 8; e++) acc8[e] += bf2f(a[e]);
    }
    u16x8 ov;
#pragma unroll
    for (int e = 0; e < 8; e++) ov[e] = f2bf(acc8[e] * inv);
    ((u16x8*)yp)[j] = ov;
  }
}

// ---------- residual + LayerNorm (scale only); y2 is bf16 ----------
__global__ __launch_bounds__(256) void ln_kernel(const unsigned short* __restrict__ y2,
                                                 const float* __restrict__ qin,
                                                 const float* __restrict__ lnw,
                                                 float* __restrict__ out) {
  const int row = blockIdx.x, t = threadIdx.x;
  const u16x8* Y = (const u16x8*)(y2 + (size_t)row * EMB);
  const float4* Qv = (const float4*)(qin + (size_t)row * EMB);
  u16x8 yv = Y[t];
  float4 b0 = Qv[2 * t], b1 = Qv[2 * t + 1];
  float x[8];
  x[0] = bf2f(yv[0]) + b0.x; x[1] = bf2f(yv[1]) + b0.y;
  x[2] = bf2f(yv[2]) + b0.z; x[3] = bf2f(yv[3]) + b0.w;
  x[4] = bf2f(yv[4]) + b1.x; x[5] = bf2f(yv[5]) + b1.y;
  x[6] = bf2f(yv[6]) + b1.z; x[7] = bf2f(yv[7]) + b1.w;
  float s = 0.0f, s2 = 0.0f;
#pragma unroll
  for (int j = 0; j < 8; j++) { s += x[j]; s2 += x[j] * x[j]; }
#pragma unroll
  for (int d = 1; d < 64; d <<= 1) {
    s += __shfl_xor(s, d, 64);
    s2 += __shfl_xor(s2, d, 64);
  }
  __shared__ float red[8];
  if ((t & 63) == 0) { red[(t >> 6) * 2] = s; red[(t >> 6) * 2 + 1] = s2; }
  __syncthreads();
  s = red[0] + red[2] + red[4] + red[6];
  s2 = red[1] + red[3] + red[5] + red[7];
  float mu = s * (1.0f / EMB);
  float var = s2 * (1.0f / EMB) - mu * mu;
  float r = rsqrtf(var + 1e-5f);
  const float4* Wv4 = (const float4*)lnw;
  float4 w0 = Wv4[2 * t], w1 = Wv4[2 * t + 1];
  float4 o0, o1;
  o0.x = (x[0] - mu) * r * w0.x; o0.y = (x[1] - mu) * r * w0.y;
  o0.z = (x[2] - mu) * r * w0.z; o0.w = (x[3] - mu) * r * w0.w;
  o1.x = (x[4] - mu) * r * w1.x; o1.y = (x[5] - mu) * r * w1.y;
  o1.z = (x[6] - mu) * r * w1.z; o1.w = (x[7] - mu) * r * w1.w;
  ((float4*)(out + (size_t)row * EMB))[2 * t] = o0;
  ((float4*)(out + (size_t)row * EMB))[2 * t + 1] = o1;
}

// ---------- launch ----------
extern "C" void kernel_launch(void* const* d_in, const int* in_sizes, int n_in,
                              void* d_out, int out_size, void* d_ws, size_t ws_size,
                              hipStream_t stream) {
  const float* q = (const float*)d_in[0];
  const float* k = (const float*)d_in[1];
  const float* v = (const float*)d_in[2];
  const float* Wq = (const float*)d_in[3];
  const float* Wk = (const float*)d_in[4];
  const float* Wv = (const float*)d_in[5];
  const float* Wo = (const float*)d_in[6];
  const float* lnw = (const float*)d_in[7];
  float* out = (float*)d_out;
  char* ws = (char*)d_ws;

  const size_t WB = (size_t)EMB * EMB * 2;       // 8 MB  (bf16 weight)
  const size_t XB = (size_t)TSEQ * EMB * 2;      // 16 MB (bf16 activation)
  unsigned short* Wq_b = (unsigned short*)(ws + 0 * WB);
  unsigned short* Wk_b = (unsigned short*)(ws + 1 * WB);
  unsigned short* Wv_b = (unsigned short*)(ws + 2 * WB);
  unsigned short* Wo_b = (unsigned short*)(ws + 3 * WB);
  unsigned short* qb   = (unsigned short*)(ws + 4 * WB);
  unsigned short* kb   = (unsigned short*)(ws + 4 * WB + XB);
  unsigned short* vb   = (unsigned short*)(ws + 4 * WB + 2 * XB);
  unsigned short* Qb   = (unsigned short*)(ws + 4 * WB + 3 * XB);
  unsigned short* Kb   = (unsigned short*)(ws + 4 * WB + 4 * XB);
  unsigned short* Vtb  = (unsigned short*)(ws + 4 * WB + 5 * XB);
  unsigned short* yb   = qb;                                   // merge out (qb dead after QKV proj)
  // During attn: [0,24MB) = slotsLo (over dead Wq/Wk/Wv_b), [48,64) = slotsHi (over dead kb),
  // lbuf over dead vb. After merge: y2 over dead Qb.
  unsigned short* slotsLo = (unsigned short*)(ws);                       // 768 slots = 24 MB
  unsigned short* slotsHi = (unsigned short*)(ws + 4 * WB + XB);         // 512 slots = 16 MB
  float* lbuf = (float*)(ws + 4 * WB + 2 * XB);                          // 1280*128*4 = 655 KB
  unsigned short* y2 = Qb;                                               // bf16 gemm_o out (16 MB)

  cvt_all<<<20480, 256, 0, stream>>>(q, k, v, Wq, Wk, Wv, Wo,
                                     qb, kb, vb, Wq_b, Wk_b, Wv_b, Wo_b);

  gemm_qkv<<<1536, 256, 0, stream>>>(qb, kb, vb, Wq_b, Wk_b, Wv_b, Qb, Kb, Vtb);

  attn_kernel<<<1024, 256, 0, stream>>>(Qb, Kb, Vtb, slotsLo, slotsHi, lbuf);

  merge_kernel<<<512, 256, 0, stream>>>(slotsLo, slotsHi, lbuf, yb);

  gemm_o<<<dim3(16, 32), 256, 0, stream>>>(yb, Wo_b, y2);

  ln_kernel<<<TSEQ, 256, 0, stream>>>(y2, q, lnw, out);
}

// Round 14
// 324.957 us; speedup vs baseline: 1.5734x; 1.5734x over previous
//
#include <hip/hip_runtime.h>

typedef __bf16 bf16x8 __attribute__((ext_vector_type(8)));
typedef __bf16 bf16x2_t __attribute__((ext_vector_type(2)));
typedef float f32x4 __attribute__((ext_vector_type(4)));
typedef float f32x16 __attribute__((ext_vector_type(16)));
typedef unsigned int u32x4 __attribute__((ext_vector_type(4)));
typedef unsigned short u16x8 __attribute__((ext_vector_type(8)));

#define EMB 2048
#define NH 16
#define HD 128
#define TSEQ 4096

// ---------- helpers ----------
__device__ __forceinline__ unsigned short f2bf(float x) {
  unsigned int u = __builtin_bit_cast(unsigned int, x);
  u += 0x7fffu + ((u >> 16) & 1u);   // RNE
  return (unsigned short)(u >> 16);
}

__device__ __forceinline__ float bf2f(unsigned short u) {
  unsigned int x = ((unsigned int)u) << 16;
  return __builtin_bit_cast(float, x);
}

__device__ __forceinline__ float ex2(float x) { return __builtin_amdgcn_exp2f(x); }

__device__ __forceinline__ void gl_lds16(const void* g, void* l) {
  __builtin_amdgcn_global_load_lds((__attribute__((address_space(1))) void*)(void*)g,
                                   (__attribute__((address_space(3))) void*)l, 16, 0, 0);
}

template <typename OutT>
__device__ __forceinline__ void store_out(OutT* p, float v) {
  if constexpr (sizeof(OutT) == 2) { *p = f2bf(v); } else { *p = v; }
}

// ---------- fused fp32 -> bf16 convert for all 7 tensors ----------
__global__ __launch_bounds__(256) void cvt_all(const float* __restrict__ q, const float* __restrict__ k,
                                               const float* __restrict__ v, const float* __restrict__ Wq,
                                               const float* __restrict__ Wk, const float* __restrict__ Wv,
                                               const float* __restrict__ Wo,
                                               unsigned short* qb, unsigned short* kb, unsigned short* vb,
                                               unsigned short* Wqb, unsigned short* Wkb, unsigned short* Wvb,
                                               unsigned short* Wob) {
  const int SX = TSEQ * EMB / 8;   // 2^20
  const int SW = EMB * EMB / 8;    // 2^19
  int i = blockIdx.x * 256 + threadIdx.x;
  const float* src; unsigned short* dst; int off;
  if (i < 3 * SX) {
    int seg = i >> 20; off = i & (SX - 1);
    src = (seg == 0) ? q : (seg == 1) ? k : v;
    dst = (seg == 0) ? qb : (seg == 1) ? kb : vb;
  } else {
    int j = i - 3 * SX;
    int seg = j >> 19; off = j & (SW - 1);
    src = (seg == 0) ? Wq : (seg == 1) ? Wk : (seg == 2) ? Wv : Wo;
    dst = (seg == 0) ? Wqb : (seg == 1) ? Wkb : (seg == 2) ? Wvb : Wob;
  }
  const float4* p = (const float4*)src + (size_t)off * 2;
  float4 a = p[0], b = p[1];
  u32x4 r;
  r.x = (unsigned)f2bf(a.x) | ((unsigned)f2bf(a.y) << 16);
  r.y = (unsigned)f2bf(a.z) | ((unsigned)f2bf(a.w) << 16);
  r.z = (unsigned)f2bf(b.x) | ((unsigned)f2bf(b.y) << 16);
  r.w = (unsigned)f2bf(b.z) | ((unsigned)f2bf(b.w) << 16);
  ((u32x4*)dst)[off] = r;
}

// ---------- NT GEMM body: C[M,N] = A[M,K] * B[N,K]^T  (128x128 tile, BK=32) ----------
// r8's proven staging/sync structure (counted-vmcnt double-buffer, both-side swizzle).
template <typename OutT>
__device__ __forceinline__ void gemm_body(const unsigned short* __restrict__ A,
                                          const unsigned short* __restrict__ B,
                                          OutT* __restrict__ C,
                                          int m0, int n0, int N, int K, char* smem, float oscale) {
  const int t = threadIdx.x;
  const int l = t & 63, lg = l >> 4, l15 = l & 15;
  const int w = t >> 6, wm = w >> 1, wn = w & 1;

  f32x4 acc[4][4] = {};

  const int rowS = t >> 2;
  const int cbS = (t & 3) * 16;
  const int swS = cbS ^ ((rowS & 3) << 4);        // pre-swizzled source column byte
  const char* Ab = (const char*)A + ((size_t)(m0 + rowS) * K) * 2;
  const char* Bb = (const char*)B + ((size_t)(n0 + rowS) * K) * 2;
  const size_t rowStep = (size_t)64 * K * 2;

  auto stage = [&](int buf, int kt) {
    const int ktB = kt * 2;
    char* sA = smem + buf * 8192;
    char* sB = smem + 16384 + buf * 8192;
    gl_lds16(Ab + ktB + swS, sA + t * 16);
    gl_lds16(Ab + rowStep + ktB + swS, sA + 4096 + t * 16);   // (row+64)&3 == row&3
    gl_lds16(Bb + ktB + swS, sB + t * 16);
    gl_lds16(Bb + rowStep + ktB + swS, sB + 4096 + t * 16);
  };

  const int nIter = K / 32;
  stage(0, 0);
  int cur = 0;
  for (int it = 0; it < nIter; ++it) {
    if (it + 1 < nIter) {
      stage(cur ^ 1, (it + 1) * 32);
      asm volatile("s_waitcnt vmcnt(4)" ::: "memory");   // wait only for CURRENT tile's stage
    } else {
      asm volatile("s_waitcnt vmcnt(0)" ::: "memory");
    }
    __builtin_amdgcn_s_barrier();

    const char* sA = smem + cur * 8192;
    const char* sB = smem + 16384 + cur * 8192;
    const int rsw = (l15 & 3) << 4;                      // read-side XOR (rows mod 4 = l15&3)
    bf16x8 af[4], bfr[4];
#pragma unroll
    for (int m = 0; m < 4; m++) {
      const int r = wm * 64 + m * 16 + l15;
      af[m] = *(const bf16x8*)(sA + r * 64 + ((lg * 16) ^ rsw));
    }
#pragma unroll
    for (int n = 0; n < 4; n++) {
      const int r = wn * 64 + n * 16 + l15;
      bfr[n] = *(const bf16x8*)(sB + r * 64 + ((lg * 16) ^ rsw));
    }
#pragma unroll
    for (int m = 0; m < 4; m++)
#pragma unroll
      for (int n = 0; n < 4; n++)
        acc[m][n] = __builtin_amdgcn_mfma_f32_16x16x32_bf16(af[m], bfr[n], acc[m][n], 0, 0, 0);

    __builtin_amdgcn_s_barrier();   // all waves done reading buf[cur] before it is restaged
    cur ^= 1;
  }

#pragma unroll
  for (int m = 0; m < 4; m++) {
    int row = m0 + wm * 64 + m * 16 + 4 * lg;
#pragma unroll
    for (int n = 0; n < 4; n++) {
      int col = n0 + wn * 64 + n * 16 + l15;
#pragma unroll
      for (int i = 0; i < 4; i++)
        store_out(C + (size_t)(row + i) * N + col, acc[m][n][i] * oscale);
    }
  }
}

// Fused Q/K/V projections: 1536 blocks, linear grid (r8's proven mapping).
// Q output pre-scaled by 1/sqrt(HD)*log2(e) so attention softmax runs in exp2 domain.
__global__ __launch_bounds__(256) void gemm_qkv(const unsigned short* __restrict__ qb,
                                                const unsigned short* __restrict__ kb,
                                                const unsigned short* __restrict__ vb,
                                                const unsigned short* __restrict__ Wq,
                                                const unsigned short* __restrict__ Wk,
                                                const unsigned short* __restrict__ Wv,
                                                unsigned short* Qo, unsigned short* Ko, unsigned short* Vto) {
  __shared__ char smem[32768];
  const int bx = blockIdx.x;
  const int z = bx >> 9, r = bx & 511;
  const unsigned short* A; const unsigned short* B; unsigned short* C;
  int N, m0, n0; float sc;
  if (z == 0)      { A = qb; B = Wq; C = Qo;  N = EMB;  n0 = (r & 15) << 7; m0 = (r >> 4) << 7; sc = 0.12751743f; }
  else if (z == 1) { A = kb; B = Wk; C = Ko;  N = EMB;  n0 = (r & 15) << 7; m0 = (r >> 4) << 7; sc = 1.0f; }
  else             { A = Wv; B = vb; C = Vto; N = TSEQ; n0 = (r & 31) << 7; m0 = (r >> 5) << 7; sc = 1.0f; }
  gemm_body<unsigned short>(A, B, C, m0, n0, N, EMB, smem, sc);
}

// Output projection -> bf16 y2 (halves y2 traffic; LN reads bf16).
__global__ __launch_bounds__(256) void gemm_o(const unsigned short* __restrict__ A,
                                              const unsigned short* __restrict__ B,
                                              unsigned short* __restrict__ C) {
  __shared__ char smem[32768];
  gemm_body<unsigned short>(A, B, C, blockIdx.y * 128, blockIdx.x * 128, EMB, EMB, smem, 1.0f);
}

// ---------- flash attention (causal), swapped-QK^T, 32x32x16 MFMA, static-max softmax ----------
// 512 UNIFORM blocks of exactly 33 kv-iterations each (kv-split pairing, see r5).
__global__ __launch_bounds__(256, 2) void attn_kernel(const unsigned short* __restrict__ Q,
                                                      const unsigned short* __restrict__ Kp,
                                                      const unsigned short* __restrict__ Vt,
                                                      unsigned short* __restrict__ slots,
                                                      float* __restrict__ lbuf) {
  __shared__ char sK[2][16384];  // [64 kv][128 hd] bf16, 256B rows, xor-swz (&15)
  __shared__ char sV[3][16384];  // [128 hd][64 kv] bf16, 128B rows, xor-swz (&7)
  const int t = threadIdx.x, l = t & 63, w = t >> 6;
  const int l31 = l & 31, hh = l >> 5;
  const int b = blockIdx.x;
  const int h = b >> 5;
  const int p = (b >> 1) & 15;
  const int half = b & 1;
  const int slotBase = (h * 16 + p) * 3;

  const int q0A = 128 * p, q0B = 128 * (31 - p);
  const int swi = (half == 0) ? (2 * p + 2) : 64;   // gi at which tile B starts (64 = never)
  const int kvOff = 31 - 2 * p;                     // half-1 kv-block offset

  int q0 = (half == 0) ? q0A : q0B;
  int qrow = q0 + w * 32 + l31;

  auto kvof = [&](int gi) -> int {
    if (half == 0) return (gi < swi) ? gi * 64 : (gi - swi) * 64;
    return (kvOff + gi) * 64;
  };

  bf16x8 qf[8];
#pragma unroll
  for (int kd = 0; kd < 8; kd++)
    qf[kd] = *(const bf16x8*)(Q + (size_t)qrow * EMB + h * HD + kd * 16 + hh * 8);

  f32x16 o[4] = {};
  float l_run = 0.0f;

  const int rK = t >> 4, cK = (t & 15) * 16;
  const int rV = t >> 3, cV = (t & 7) * 16;
  const char* Kb = (const char*)Kp;
  const char* Vb = (const char*)Vt;

  auto stage = [&](int kbuf, int vbuf, int kv0) {
#pragma unroll
    for (int c = 0; c < 4; c++) {
      int rowK = c * 16 + rK;
      gl_lds16(Kb + (size_t)(kv0 + rowK) * (EMB * 2) + h * (HD * 2) + (cK ^ ((rowK & 15) << 4)),
               sK[kbuf] + c * 4096 + t * 16);
      int rowV = c * 32 + rV;
      gl_lds16(Vb + (size_t)(h * HD + rowV) * (TSEQ * 2) + kv0 * 2 + (cV ^ ((rowV & 7) << 4)),
               sV[vbuf] + c * 4096 + t * 16);
    }
  };

  auto writeout = [&](int slotId) {
    unsigned short* S = slots + (size_t)slotId * (128 * 128);
    const int r = w * 32 + l31;
    float lt = l_run + __shfl_xor(l_run, 32, 64);
    if (hh == 0) lbuf[slotId * 128 + r] = lt;
#pragma unroll
    for (int hdm = 0; hdm < 4; hdm++)
#pragma unroll
      for (int rq = 0; rq < 4; rq++) {
        ushort4 st;
        st.x = f2bf(o[hdm][4 * rq + 0]);
        st.y = f2bf(o[hdm][4 * rq + 1]);
        st.z = f2bf(o[hdm][4 * rq + 2]);
        st.w = f2bf(o[hdm][4 * rq + 3]);
        *(ushort4*)(S + r * 128 + hdm * 32 + 8 * rq + 4 * hh) = st;
      }
  };

  stage(0, 0, kvof(0));
  int kc = 0, vc = 0, vn = 1;
  for (int gi = 0; gi < 33; ++gi) {
    if (half == 0 && gi == swi) {
      writeout(slotBase + 0);
#pragma unroll
      for (int hdm = 0; hdm < 4; hdm++)
#pragma unroll
        for (int i = 0; i < 16; i++) o[hdm][i] = 0.0f;
      l_run = 0.0f;
      q0 = q0B;
      qrow = q0 + w * 32 + l31;
#pragma unroll
      for (int kd = 0; kd < 8; kd++)
        qf[kd] = *(const bf16x8*)(Q + (size_t)qrow * EMB + h * HD + kd * 16 + hh * 8);
    }
    const int kv0 = kvof(gi);
    if (gi + 1 < 33) {
      stage(kc ^ 1, vn, kvof(gi + 1));
      asm volatile("s_waitcnt vmcnt(8)" ::: "memory");
    } else {
      asm volatile("s_waitcnt vmcnt(0)" ::: "memory");
    }
    __builtin_amdgcn_s_barrier();

    const char* KB = sK[kc];
    const char* VB = sV[vc];

    f32x16 s[2];
#pragma unroll
    for (int i = 0; i < 16; i++) { s[0][i] = -8.0f; s[1][i] = -8.0f; }
    __builtin_amdgcn_s_setprio(1);
#pragma unroll
    for (int kvm = 0; kvm < 2; kvm++) {
      const int rowA = kvm * 32 + l31;
      const int swz = (rowA & 15) << 4;
#pragma unroll
      for (int kd = 0; kd < 8; kd++) {
        bf16x8 kf = *(const bf16x8*)(KB + rowA * 256 + ((kd * 32 + hh * 16) ^ swz));
        s[kvm] = __builtin_amdgcn_mfma_f32_32x32x16_bf16(kf, qf[kd], s[kvm], 0, 0, 0);
      }
    }
    __builtin_amdgcn_s_setprio(0);
    __builtin_amdgcn_s_barrier();

    const bool diag = (kv0 + 64 > q0);
    if (diag) {
#pragma unroll
      for (int kvm = 0; kvm < 2; kvm++)
#pragma unroll
        for (int i = 0; i < 16; i++)
          if (kv0 + kvm * 32 + (i & 3) + 8 * (i >> 2) + 4 * hh > qrow) s[kvm][i] = -1e30f;
    }
    float psum = 0.0f;
    unsigned int wb[16];
#pragma unroll
    for (int kvm = 0; kvm < 2; kvm++)
#pragma unroll
      for (int m = 0; m < 8; m++) {
        float p0 = ex2(s[kvm][2 * m + 0]);
        float p1 = ex2(s[kvm][2 * m + 1]);
        psum += p0 + p1;
        bf16x2_t pk; pk[0] = (__bf16)p0; pk[1] = (__bf16)p1;
        wb[kvm * 8 + m] = __builtin_bit_cast(unsigned int, pk);
      }
    l_run += psum;

    __builtin_amdgcn_s_setprio(1);
#pragma unroll
    for (int kvm = 0; kvm < 2; kvm++)
#pragma unroll
      for (int sx = 0; sx < 2; sx++) {
        const int base = kvm * 8 + 4 * sx;
        const unsigned int a0 = wb[base + 0], a1 = wb[base + 1];
        const unsigned int b0 = wb[base + 2], b1 = wb[base + 3];
        const unsigned int snd0 = hh ? a0 : b0;
        const unsigned int snd1 = hh ? a1 : b1;
        const unsigned int rcv0 = (unsigned int)__shfl_xor((int)snd0, 32, 64);
        const unsigned int rcv1 = (unsigned int)__shfl_xor((int)snd1, 32, 64);
        u32x4 pw;
        pw.x = hh ? rcv0 : a0;
        pw.y = hh ? rcv1 : a1;
        pw.z = hh ? b0 : rcv0;
        pw.w = hh ? b1 : rcv1;
        const bf16x8 pfrag = __builtin_bit_cast(bf16x8, pw);
        const int ks = kvm * 2 + sx;
#pragma unroll
        for (int hdm = 0; hdm < 4; hdm++) {
          const int rowA = hdm * 32 + l31;
          bf16x8 vf = *(const bf16x8*)(VB + rowA * 128 + ((ks * 32 + hh * 16) ^ ((rowA & 7) << 4)));
          o[hdm] = __builtin_amdgcn_mfma_f32_32x32x16_bf16(vf, pfrag, o[hdm], 0, 0, 0);
        }
      }
    __builtin_amdgcn_s_setprio(0);

    kc ^= 1;
    vc = vn;
    vn = (vn == 2) ? 0 : vn + 1;
  }

  writeout(slotBase + ((half == 0) ? 1 : 2));
}

// ---------- merge partials -> normalized bf16 y ----------
__global__ __launch_bounds__(256) void merge_kernel(const unsigned short* __restrict__ slots,
                                                    const float* __restrict__ lbuf,
                                                    unsigned short* __restrict__ Y) {
  const int tile = blockIdx.x;
  const int h = tile >> 5, tt = tile & 31;
  const int p = (tt <= 15) ? tt : 31 - tt;
  const int base = (h * 16 + p) * 3;
  const int t = threadIdx.x;
  const int r = t >> 1;
  const int c0 = (t & 1) * 64;
  unsigned short* yp = Y + (size_t)(128 * tt + r) * EMB + h * HD + c0;
  if (tt <= 15) {
    const unsigned short* S = slots + (size_t)(base + 0) * (128 * 128) + r * 128 + c0;
    const float inv = 1.0f / lbuf[(base + 0) * 128 + r];
#pragma unroll
    for (int j = 0; j < 8; j++) {
      u16x8 a = ((const u16x8*)S)[j];
      u16x8 ov;
#pragma unroll
      for (int e = 0; e < 8; e++) ov[e] = f2bf(bf2f(a[e]) * inv);
      ((u16x8*)yp)[j] = ov;
    }
  } else {
    const unsigned short* S0 = slots + (size_t)(base + 1) * (128 * 128) + r * 128 + c0;
    const unsigned short* S1 = slots + (size_t)(base + 2) * (128 * 128) + r * 128 + c0;
    const float inv = 1.0f / (lbuf[(base + 1) * 128 + r] + lbuf[(base + 2) * 128 + r]);
#pragma unroll
    for (int j = 0; j < 8; j++) {
      u16x8 a = ((const u16x8*)S0)[j];
      u16x8 c = ((const u16x8*)S1)[j];
      u16x8 ov;
#pragma unroll
      for (int e = 0; e < 8; e++) ov[e] = f2bf((bf2f(a[e]) + bf2f(c[e])) * inv);
      ((u16x8*)yp)[j] = ov;
    }
  }
}

// ---------- residual + LayerNorm (scale only); y2 is bf16 ----------
__global__ __launch_bounds__(256) void ln_kernel(const unsigned short* __restrict__ y2,
                                                 const float* __restrict__ qin,
                                                 const float* __restrict__ lnw,
                                                 float* __restrict__ out) {
  const int row = blockIdx.x, t = threadIdx.x;
  const u16x8* Y = (const u16x8*)(y2 + (size_t)row * EMB);
  const float4* Qv = (const float4*)(qin + (size_t)row * EMB);
  u16x8 yv = Y[t];
  float4 b0 = Qv[2 * t], b1 = Qv[2 * t + 1];
  float x[8];
  x[0] = bf2f(yv[0]) + b0.x; x[1] = bf2f(yv[1]) + b0.y;
  x[2] = bf2f(yv[2]) + b0.z; x[3] = bf2f(yv[3]) + b0.w;
  x[4] = bf2f(yv[4]) + b1.x; x[5] = bf2f(yv[5]) + b1.y;
  x[6] = bf2f(yv[6]) + b1.z; x[7] = bf2f(yv[7]) + b1.w;
  float s = 0.0f, s2 = 0.0f;
#pragma unroll
  for (int j = 0; j < 8; j++) { s += x[j]; s2 += x[j] * x[j]; }
#pragma unroll
  for (int d = 1; d < 64; d <<= 1) {
    s += __shfl_xor(s, d, 64);
    s2 += __shfl_xor(s2, d, 64);
  }
  __shared__ float red[8];
  if ((t & 63) == 0) { red[(t >> 6) * 2] = s; red[(t >> 6) * 2 + 1] = s2; }
  __syncthreads();
  s = red[0] + red[2] + red[4] + red[6];
  s2 = red[1] + red[3] + red[5] + red[7];
  float mu = s * (1.0f / EMB);
  float var = s2 * (1.0f / EMB) - mu * mu;
  float r = rsqrtf(var + 1e-5f);
  const float4* Wv4 = (const float4*)lnw;
  float4 w0 = Wv4[2 * t], w1 = Wv4[2 * t + 1];
  float4 o0, o1;
  o0.x = (x[0] - mu) * r * w0.x; o0.y = (x[1] - mu) * r * w0.y;
  o0.z = (x[2] - mu) * r * w0.z; o0.w = (x[3] - mu) * r * w0.w;
  o1.x = (x[4] - mu) * r * w1.x; o1.y = (x[5] - mu) * r * w1.y;
  o1.z = (x[6] - mu) * r * w1.z; o1.w = (x[7] - mu) * r * w1.w;
  ((float4*)(out + (size_t)row * EMB))[2 * t] = o0;
  ((float4*)(out + (size_t)row * EMB))[2 * t + 1] = o1;
}

// ---------- launch ----------
extern "C" void kernel_launch(void* const* d_in, const int* in_sizes, int n_in,
                              void* d_out, int out_size, void* d_ws, size_t ws_size,
                              hipStream_t stream) {
  const float* q = (const float*)d_in[0];
  const float* k = (const float*)d_in[1];
  const float* v = (const float*)d_in[2];
  const float* Wq = (const float*)d_in[3];
  const float* Wk = (const float*)d_in[4];
  const float* Wv = (const float*)d_in[5];
  const float* Wo = (const float*)d_in[6];
  const float* lnw = (const float*)d_in[7];
  float* out = (float*)d_out;
  char* ws = (char*)d_ws;

  const size_t WB = (size_t)EMB * EMB * 2;       // 8 MB  (bf16 weight)
  const size_t XB = (size_t)TSEQ * EMB * 2;      // 16 MB (bf16 activation)
  unsigned short* Wq_b = (unsigned short*)(ws + 0 * WB);
  unsigned short* Wk_b = (unsigned short*)(ws + 1 * WB);
  unsigned short* Wv_b = (unsigned short*)(ws + 2 * WB);
  unsigned short* Wo_b = (unsigned short*)(ws + 3 * WB);
  unsigned short* qb   = (unsigned short*)(ws + 4 * WB);
  unsigned short* kb   = (unsigned short*)(ws + 4 * WB + XB);
  unsigned short* vb   = (unsigned short*)(ws + 4 * WB + 2 * XB);
  unsigned short* Qb   = (unsigned short*)(ws + 4 * WB + 3 * XB);
  unsigned short* Kb   = (unsigned short*)(ws + 4 * WB + 4 * XB);
  unsigned short* Vtb  = (unsigned short*)(ws + 4 * WB + 5 * XB);
  unsigned short* yb   = qb;                         // reuse (qb dead after QKV proj)
  unsigned short* slots = (unsigned short*)(ws + 4 * WB + XB);                       // 24 MB
  float* lbuf = (float*)(ws + 4 * WB + XB + (size_t)768 * 128 * 128 * 2);            // 393 KB
  unsigned short* y2 = (unsigned short*)(ws + 4 * WB + XB);   // bf16 gemm_o out (over slots, post-merge)

  cvt_all<<<20480, 256, 0, stream>>>(q, k, v, Wq, Wk, Wv, Wo,
                                     qb, kb, vb, Wq_b, Wk_b, Wv_b, Wo_b);

  gemm_qkv<<<1536, 256, 0, stream>>>(qb, kb, vb, Wq_b, Wk_b, Wv_b, Qb, Kb, Vtb);

  attn_kernel<<<512, 256, 0, stream>>>(Qb, Kb, Vtb, slots, lbuf);

  merge_kernel<<<512, 256, 0, stream>>>(slots, lbuf, yb);

  gemm_o<<<dim3(16, 32), 256, 0, stream>>>(yb, Wo_b, y2);

  ln_kernel<<<TSEQ, 256, 0, stream>>>(y2, q, lnw, out);
}